// Round 22
// baseline (2001.626 us; speedup 1.0000x reference)
//
#include <hip/hip_runtime.h>
#include <hip/hip_cooperative_groups.h>
#include <math.h>

namespace cg = cooperative_groups;

#define T_DIM 512
#define B_DIM 256
#define D_DIM 256
#define H_DIM 256
#define G_DIM 1024   // 4*H
#define K_DIM 512    // D + H
#define NROUNDS 40
#define CHAIN_K 16   // rounds 0..15 batched; steps >=16 via per-segment finisher

typedef __attribute__((ext_vector_type(8))) short short8;
typedef __attribute__((ext_vector_type(4))) float f32x4;

__device__ __forceinline__ unsigned int f2bf(float f) {
    unsigned int b = __float_as_uint(f);
    return (b + 0x7FFFu + ((b >> 16) & 1u)) >> 16;   // round-to-nearest-even bf16
}
__device__ __forceinline__ unsigned long long pack4(float4 v) {
    const unsigned int lo = (f2bf(v.y) << 16) | f2bf(v.x);
    const unsigned int hi = (f2bf(v.w) << 16) | f2bf(v.z);
    return ((unsigned long long)hi << 32) | lo;
}
__device__ __forceinline__ float sigm(float x) { return 1.0f / (1.0f + __expf(-x)); }
__device__ __forceinline__ float tanh_fast(float x) { return 2.0f / (1.0f + __expf(-2.0f * x)) - 1.0f; }

// async 16B/lane global->LDS (dest = wave-uniform base + lane*16; SOURCE is per-lane)
__device__ __forceinline__ void dma16(const void* g, void* l) {
    __builtin_amdgcn_global_load_lds(
        (const __attribute__((address_space(1))) void*)g,
        (__attribute__((address_space(3))) void*)l, 16, 0, 0);
}

// Prepack W into MFMA B-fragment order, bf16.
// short idx ((nt*16+ks)*64+l)*8+j  <->  g = nt*16+(l&15), k = ks*32+((l>>4)<<3)+j
__global__ __launch_bounds__(256) void k_prep_weights(
    const float* __restrict__ W_ih, const float* __restrict__ W_hh,
    const float* __restrict__ b_ih, const float* __restrict__ b_hh,
    unsigned int* __restrict__ Wb, float* __restrict__ bias)
{
    const int idx = blockIdx.x * 256 + threadIdx.x;   // 0 .. 262143
    const int jp = idx & 3, l = (idx >> 2) & 63, ks = (idx >> 8) & 15, nt = idx >> 12;
    const int g = nt * 16 + (l & 15);
    const int k0 = ks * 32 + ((l >> 4) << 3) + 2 * jp;
    const float w0 = (k0 < D_DIM) ? W_ih[g * D_DIM + k0] : W_hh[g * H_DIM + (k0 - D_DIM)];
    const float w1 = (k0 + 1 < D_DIM) ? W_ih[g * D_DIM + k0 + 1] : W_hh[g * H_DIM + (k0 + 1 - D_DIM)];
    Wb[idx] = (f2bf(w1) << 16) | f2bf(w0);
    if (idx < G_DIM) bias[idx] = b_ih[idx] + b_hh[idx];
}

// Prepack W k-major for the finisher GEMV.
__global__ __launch_bounds__(256) void k_prep_wq(
    const float* __restrict__ W_ih, const float* __restrict__ W_hh,
    unsigned long long* __restrict__ Wq)
{
    const int idx = blockIdx.x * 256 + threadIdx.x;   // 0..131071
    const int kq = idx >> 10, g = idx & (G_DIM - 1);
    float w[4];
    #pragma unroll
    for (int j = 0; j < 4; ++j) {
        const int k = kq * 4 + j;
        w[j] = (k < D_DIM) ? W_ih[g * D_DIM + k] : W_hh[g * H_DIM + (k - D_DIM)];
    }
    Wq[idx] = pack4((float4){w[0], w[1], w[2], w[3]});
}

// Fused ab prep: wave = one pos row. x-half bf16 + h-half prefill (reset->0, t0->h0).
__global__ __launch_bounds__(256) void k_prep_ab(
    const float* __restrict__ x, const float* __restrict__ h0,
    const int* __restrict__ done, unsigned long long* __restrict__ ab_u64)
{
    const int pos = (blockIdx.x * 256 + threadIdx.x) >> 6;   // row = wave index
    const int l = threadIdx.x & 63;
    const float4 xv = *(const float4*)(x + (size_t)pos * D_DIM + l * 4);
    ab_u64[(size_t)pos * 128 + l] = pack4(xv);               // x-half slots [0,64)
    const int d = done[pos];
    if (d || pos < B_DIM) {
        unsigned long long hv = 0ull;
        if (!d) {   // t==0 row, carry h0
            const float4 h = *(const float4*)(h0 + (size_t)(pos & (B_DIM - 1)) * H_DIM + l * 4);
            hv = pack4(h);
        }
        ab_u64[(size_t)pos * 128 + 64 + l] = hv;             // h-half slots [64,128)
    }
}

// Parallel kmap + histogram (kmap = TRUE steps since reset; bins clamp).
__global__ __launch_bounds__(256) void k_kmap(
    const int* __restrict__ done, int* __restrict__ kmap, int* __restrict__ counts)
{
    __shared__ int lcnt[NROUNDS];
    const int tid = threadIdx.x;
    if (tid < NROUNDS) lcnt[tid] = 0;
    __syncthreads();
    const int t = blockIdx.x, b = tid;
    int kv = t;
    for (int tt = t; tt >= 0; --tt) {
        if (done[tt * B_DIM + b]) { kv = t - tt; break; }
    }
    kmap[t * B_DIM + b] = kv;
    const int bin = kv < NROUNDS ? kv : NROUNDS - 1;
    atomicAdd(&lcnt[bin], 1);
    __syncthreads();
    if (tid < NROUNDS && lcnt[tid] > 0) atomicAdd(&counts[tid], lcnt[tid]);
}

__global__ __launch_bounds__(64) void k_offs(
    const int* __restrict__ counts, int* __restrict__ offs, int* __restrict__ cursor)
{
    if (threadIdx.x == 0) {
        int s = 0;
        for (int i = 0; i < NROUNDS; ++i) { offs[i] = s; s += counts[i]; }
    }
    if (threadIdx.x < NROUNDS) cursor[threadIdx.x] = 0;
}

// Two-level scatter: LDS local ranks + one global atomicAdd per (block, bin).
__global__ __launch_bounds__(256) void k_scatter(
    const int* __restrict__ kmap, const int* __restrict__ offs,
    int* __restrict__ cursor, int* __restrict__ rowlist)
{
    __shared__ int lcnt[NROUNDS];
    __shared__ int gbase[NROUNDS];
    const int tid = threadIdx.x;
    if (tid < NROUNDS) lcnt[tid] = 0;
    __syncthreads();
    const int pos = blockIdx.x * 256 + tid;
    const int kv0 = kmap[pos];
    const int kv = kv0 < NROUNDS ? kv0 : NROUNDS - 1;
    const int lrank = atomicAdd(&lcnt[kv], 1);
    __syncthreads();
    if (tid < NROUNDS && lcnt[tid] > 0) gbase[tid] = atomicAdd(&cursor[tid], lcnt[tid]);
    __syncthreads();
    rowlist[offs[kv] + gbase[kv] + lrank] = pos;
}

// ---- shared tile-loop body (champion structure) used by both round kernels ----
#define ROUND_BODY(AB, C0, DONE, COUNTS, OFFS, ROWLIST, OUT, CBUF, ABW, KK)       \
    {                                                                             \
        const int nk = COUNTS[KK];                                                \
        const int base = OFFS[KK];                                                \
        const int ntiles = (nk + 31) >> 5;                                        \
        int rt = rt0;                                                             \
        if (rt < ntiles) {                                                        \
            int posC[4], dnC[4], dsC[4]; float cpC[4];                            \
            LOAD_NEXT(rt * 32, posC, cpC, dnC, dsC, KK);                          \
            ISSUE_A(posC, 0);                                                     \
            int buf = 0;                                                          \
            for (; rt < ntiles; rt += rstride) {                                  \
                const int row0 = rt * 32;                                         \
                asm volatile("s_waitcnt vmcnt(0) lgkmcnt(0)" ::: "memory");       \
                __builtin_amdgcn_sched_barrier(0);                                \
                __builtin_amdgcn_s_barrier();                                     \
                __builtin_amdgcn_sched_barrier(0);                                \
                const int rtn = rt + rstride;                                     \
                const bool more = (rtn < ntiles);                                 \
                int posN[4], dnN[4], dsN[4]; float cpN[4];                        \
                if (more) {                                                       \
                    LOAD_NEXT(rtn * 32, posN, cpN, dnN, dsN, KK);                 \
                    ISSUE_A(posN, buf ^ 1);                                       \
                }                                                                 \
                f32x4 acc0[2], acc1[2];                                           \
                acc0[0] = (f32x4){0,0,0,0}; acc0[1] = (f32x4){0,0,0,0};           \
                acc1[0] = (f32x4){0,0,0,0}; acc1[1] = (f32x4){0,0,0,0};           \
                _Pragma("unroll")                                                 \
                for (int ks = 0; ks < 16; ++ks) {                                 \
                    _Pragma("unroll")                                             \
                    for (int mb = 0; mb < 2; ++mb) {                              \
                        const short8 a = *(const short8*)&A_lds[buf * 16384       \
                            + (mb * 16 + lc) * 512 + (((ks * 4 + lr) ^ lc) << 3)];\
                        acc0[mb] = __builtin_amdgcn_mfma_f32_16x16x32_bf16(       \
                            a, breg0[ks], acc0[mb], 0, 0, 0);                     \
                        acc1[mb] = __builtin_amdgcn_mfma_f32_16x16x32_bf16(       \
                            a, breg1[ks], acc1[mb], 0, 0, 0);                     \
                    }                                                             \
                }                                                                 \
                _Pragma("unroll")                                                 \
                for (int mb = 0; mb < 2; ++mb) {                                  \
                    *(f32x4*)&scr[(((2 * gth + 0) * 64 + q * 16 + lc) * 36)       \
                                  + mb * 16 + lr * 4] = acc0[mb];                 \
                    *(f32x4*)&scr[(((2 * gth + 1) * 64 + q * 16 + lc) * 36)       \
                                  + mb * 16 + lr * 4] = acc1[mb];                 \
                }                                                                 \
                asm volatile("s_waitcnt lgkmcnt(0)" ::: "memory");                \
                __builtin_amdgcn_sched_barrier(0);                                \
                __builtin_amdgcn_s_barrier();                                     \
                __builtin_amdgcn_sched_barrier(0);                                \
                const f32x4 vi = *(const f32x4*)&scr[((0 * 64 + l) * 36) + w * 4];\
                const f32x4 vf = *(const f32x4*)&scr[((1 * 64 + l) * 36) + w * 4];\
                const f32x4 vg = *(const f32x4*)&scr[((2 * 64 + l) * 36) + w * 4];\
                const f32x4 vo = *(const f32x4*)&scr[((3 * 64 + l) * 36) + w * 4];\
                _Pragma("unroll")                                                 \
                for (int j = 0; j < 4; ++j) {                                     \
                    const int gr = row0 + w * 4 + j;                              \
                    if (gr < nk) {                                                \
                        const int pos = posC[j];                                  \
                        const float cp = dnC[j] ? 0.0f : cpC[j];                  \
                        const float si = sigm(vi[j] + bI);                        \
                        const float sf = sigm(vf[j] + bF);                        \
                        const float tg = tanh_fast(vg[j] + bG);                   \
                        const float so = sigm(vo[j] + bO);                        \
                        const float cn = sf * cp + si * tg;                       \
                        const float hn = so * tanh_fast(cn);                      \
                        CBUF[(size_t)pos * H_DIM + u_ep] = cn;                    \
                        OUT[(size_t)pos * H_DIM + u_ep]  = hn;                    \
                        if (KK + 1 < CHAIN_K && !dsC[j])                          \
                            ABW[(size_t)(pos + B_DIM) * 512 + 256 + u_ep]         \
                                = (short)f2bf(hn);                                \
                    }                                                             \
                }                                                                 \
                _Pragma("unroll")                                                 \
                for (int j = 0; j < 4; ++j) {                                     \
                    posC[j] = posN[j]; cpC[j] = cpN[j];                           \
                    dnC[j] = dnN[j]; dsC[j] = dsN[j];                             \
                }                                                                 \
                buf ^= 1;                                                         \
            }                                                                     \
        }                                                                         \
    }

#define ISSUE_A(PP, bufv)                                                        \
    {                                                                            \
        _Pragma("unroll") for (int rr = 0; rr < 4; ++rr) {                       \
            const int r_ = w * 4 + rr;                                           \
            dma16(ab + (size_t)PP[rr] * 512 + ((l ^ (r_ & 15)) << 3),            \
                  &A_lds[(bufv) * 16384 + r_ * 512]);                            \
        }                                                                        \
    }
#define LOAD_NEXT(row0v, PP, CP, DN, DS, KK)                                     \
    {                                                                            \
        const int nkl = counts[KK]; const int basel = offs[KK];                  \
        _Pragma("unroll") for (int j_ = 0; j_ < 4; ++j_) {                       \
            const int gr_ = (row0v) + w * 4 + j_;                                \
            PP[j_] = rowlist[basel + (gr_ < nkl ? gr_ : nkl - 1)];               \
        }                                                                        \
        _Pragma("unroll") for (int j_ = 0; j_ < 4; ++j_) {                       \
            const int p_ = PP[j_];                                               \
            if (KK > 0) {                                                        \
                CP[j_] = c_buf[(size_t)(p_ - B_DIM) * H_DIM + u_ep];             \
                DN[j_] = 0;                                                      \
            } else {                                                             \
                DN[j_] = done[p_];                                               \
                CP[j_] = c0[(size_t)(p_ & (B_DIM - 1)) * H_DIM + u_ep];          \
            }                                                                    \
            const int sp_ = p_ + B_DIM;                                          \
            DS[j_] = (sp_ < T_DIM * B_DIM) ? done[sp_] : 1;                      \
        }                                                                        \
    }

// ============ cooperative all-rounds kernel (grid = 256, 1 block/CU) ============
__global__ __launch_bounds__(512, 1) void k_rounds_coop(
    const short* __restrict__ ab, const float* __restrict__ c0,
    const int* __restrict__ done,
    const short* __restrict__ Wb, const float* __restrict__ bias,
    const int* __restrict__ counts, const int* __restrict__ offs,
    const int* __restrict__ rowlist,
    float* __restrict__ out, float* __restrict__ c_buf,
    short* __restrict__ ab_w)
{
    cg::grid_group grid = cg::this_grid();
    __shared__ short A_lds[2 * 32 * 512];        // 64 KiB
    __shared__ float scr[4 * 64 * 36];           // 36 KiB

    const int tid = threadIdx.x;
    const int w = tid >> 6, l = tid & 63;
    const int lr = l >> 4, lc = l & 15;
    const int q = w & 3, gth = w >> 2;
    const int xcd = blockIdx.x & 7, slot = blockIdx.x >> 3;
    const int cb = slot & 3;
    const int rt0 = xcd * 8 + (slot >> 2);
    const int rstride = 64;
    const int u_ep = cb * 64 + l;
    const float bI = bias[u_ep], bF = bias[256 + u_ep], bG = bias[512 + u_ep], bO = bias[768 + u_ep];

    // resident B: loaded ONCE for all 16 rounds
    short8 breg0[16], breg1[16];
    {
        const int nt0 = (2 * gth + 0) * 16 + cb * 4 + q;
        const int nt1 = (2 * gth + 1) * 16 + cb * 4 + q;
        #pragma unroll
        for (int ks = 0; ks < 16; ++ks) {
            breg0[ks] = *(const short8*)(Wb + (((size_t)nt0 * 16 + ks) * 64 + l) * 8);
            breg1[ks] = *(const short8*)(Wb + (((size_t)nt1 * 16 + ks) * 64 + l) * 8);
        }
        #pragma unroll
        for (int ks = 0; ks < 16; ++ks) {
            asm volatile("" : "+v"(breg0[ks]));
            asm volatile("" : "+v"(breg1[ks]));
        }
    }

    #pragma unroll 1
    for (int kk = 0; kk < CHAIN_K; ++kk) {
        ROUND_BODY(ab, c0, done, counts, offs, rowlist, out, c_buf, ab_w, kk);
        __threadfence();   // release: round-k stores visible device-wide
        grid.sync();
        __threadfence();   // acquire: invalidate stale cross-XCD lines
    }
}

// ============ per-round kernel (fallback path, champion build) ============
__global__ __launch_bounds__(512, 1) void k_round(
    const short* __restrict__ ab, const float* __restrict__ c0,
    const int* __restrict__ done,
    const short* __restrict__ Wb, const float* __restrict__ bias,
    const int* __restrict__ counts, const int* __restrict__ offs,
    const int* __restrict__ rowlist,
    float* __restrict__ out, float* __restrict__ c_buf,
    short* __restrict__ ab_w, int kk)
{
    __shared__ short A_lds[2 * 32 * 512];
    __shared__ float scr[4 * 64 * 36];
    const int tid = threadIdx.x;
    const int w = tid >> 6, l = tid & 63;
    const int lr = l >> 4, lc = l & 15;
    const int q = w & 3, gth = w >> 2;

    int cb, rt0, rstride;
    if (gridDim.x == 256) {
        const int xcd = blockIdx.x & 7, slot = blockIdx.x >> 3;
        cb = slot & 3;
        rt0 = xcd * 8 + (slot >> 2);
        rstride = 64;
    } else {
        cb = blockIdx.x & 3;
        rt0 = blockIdx.x >> 2;
        rstride = gridDim.x >> 2;
    }
    const int u_ep = cb * 64 + l;
    const float bI = bias[u_ep], bF = bias[256 + u_ep], bG = bias[512 + u_ep], bO = bias[768 + u_ep];

    short8 breg0[16], breg1[16];
    {
        const int nt0 = (2 * gth + 0) * 16 + cb * 4 + q;
        const int nt1 = (2 * gth + 1) * 16 + cb * 4 + q;
        #pragma unroll
        for (int ks = 0; ks < 16; ++ks) {
            breg0[ks] = *(const short8*)(Wb + (((size_t)nt0 * 16 + ks) * 64 + l) * 8);
            breg1[ks] = *(const short8*)(Wb + (((size_t)nt1 * 16 + ks) * 64 + l) * 8);
        }
        #pragma unroll
        for (int ks = 0; ks < 16; ++ks) {
            asm volatile("" : "+v"(breg0[ks]));
            asm volatile("" : "+v"(breg1[ks]));
        }
    }

    ROUND_BODY(ab, c0, done, counts, offs, rowlist, out, c_buf, ab_w, kk);
}

// Per-segment sequential finisher for steps >= CHAIN_K (independent chains).
__global__ __launch_bounds__(1024) void k_finish(
    const float* __restrict__ x, const unsigned long long* __restrict__ Wq,
    const float* __restrict__ bias,
    const int* __restrict__ counts, const int* __restrict__ offs,
    const int* __restrict__ rowlist, const int* __restrict__ kmap,
    float* __restrict__ out, float* __restrict__ c_buf)
{
    __shared__ float abuf[K_DIM];
    __shared__ float dots[G_DIM];
    const int g = threadIdx.x;
    const int nch = counts[CHAIN_K];

    for (int m = blockIdx.x; m < nch; m += gridDim.x) {
        const int pos0 = rowlist[offs[CHAIN_K] + m];
        float c_u = 0.0f;
        if (g < H_DIM) {
            abuf[H_DIM + g] = out[(size_t)(pos0 - B_DIM) * H_DIM + g];
            c_u = c_buf[(size_t)(pos0 - B_DIM) * H_DIM + g];
        }
        int pos = pos0, step = CHAIN_K;
        while (true) {
            if (g < H_DIM) abuf[g] = x[(size_t)pos * D_DIM + g];
            __syncthreads();
            float dot = bias[g];
            #pragma unroll 8
            for (int kq = 0; kq < K_DIM / 4; ++kq) {
                const unsigned long long wq = Wq[(size_t)kq * G_DIM + g];
                const float4 a = *(const float4*)&abuf[kq * 4];
                const unsigned int wlo = (unsigned int)wq;
                const unsigned int whi = (unsigned int)(wq >> 32);
                const float w0 = __uint_as_float(wlo << 16);
                const float w1 = __uint_as_float(wlo & 0xFFFF0000u);
                const float w2 = __uint_as_float(whi << 16);
                const float w3 = __uint_as_float(whi & 0xFFFF0000u);
                dot = fmaf(a.x, w0, dot);
                dot = fmaf(a.y, w1, dot);
                dot = fmaf(a.z, w2, dot);
                dot = fmaf(a.w, w3, dot);
            }
            dots[g] = dot;
            __syncthreads();
            if (g < H_DIM) {
                const float si = sigm(dots[g]);
                const float sf = sigm(dots[H_DIM + g]);
                const float tg = tanh_fast(dots[2 * H_DIM + g]);
                const float so = sigm(dots[3 * H_DIM + g]);
                c_u = sf * c_u + si * tg;
                const float hn = so * tanh_fast(c_u);
                out[(size_t)pos * H_DIM + g]   = hn;
                c_buf[(size_t)pos * H_DIM + g] = c_u;
                abuf[H_DIM + g] = hn;
            }
            pos += B_DIM;
            ++step;
            __syncthreads();
            if (pos >= T_DIM * B_DIM) break;
            if (kmap[pos] != step) break;
        }
        __syncthreads();
    }
}

// hT = out rows at t=511 ; cT = c_buf at t=511
__global__ __launch_bounds__(256) void k_final(const float* __restrict__ c_buf, float* __restrict__ out)
{
    const size_t i = (size_t)blockIdx.x * 256 + threadIdx.x;
    const size_t featN = (size_t)T_DIM * B_DIM * H_DIM;
    const size_t last  = (size_t)(T_DIM - 1) * B_DIM * H_DIM;
    out[featN + i] = out[last + i];
    out[featN + (size_t)B_DIM * H_DIM + i] = c_buf[last + i];
}

__global__ __launch_bounds__(64) void k_zero(int* __restrict__ counts)
{
    if (threadIdx.x < NROUNDS) counts[threadIdx.x] = 0;
}

extern "C" void kernel_launch(void* const* d_in, const int* in_sizes, int n_in,
                              void* d_out, int out_size, void* d_ws, size_t ws_size,
                              hipStream_t stream)
{
    const float* x    = (const float*)d_in[0];
    const float* h0   = (const float*)d_in[1];
    const float* c0   = (const float*)d_in[2];
    const float* W_ih = (const float*)d_in[3];
    const float* W_hh = (const float*)d_in[4];
    const float* b_ih = (const float*)d_in[5];
    const float* b_hh = (const float*)d_in[6];
    const int*   done = (const int*)d_in[7];
    float* out = (float*)d_out;

    const size_t TB = (size_t)T_DIM * B_DIM;
    char* ws = (char*)d_ws;
    size_t off = 0;
    float* c_buf = (float*)(ws + off);            off += TB * H_DIM * 4;            // 128 MiB
    unsigned int* Wb = (unsigned int*)(ws + off); off += (size_t)(K_DIM / 2) * G_DIM * 4;
    unsigned long long* Wq = (unsigned long long*)(ws + off); off += (size_t)(K_DIM / 4) * G_DIM * 8;
    float* bias = (float*)(ws + off);             off += (size_t)G_DIM * 4;
    int* kmap    = (int*)(ws + off);              off += TB * 4;
    int* rowlist = (int*)(ws + off);              off += TB * 4;
    int* counts  = (int*)(ws + off);              off += 256;
    int* offs    = (int*)(ws + off);              off += 256;
    int* cursor  = (int*)(ws + off);              off += 256;
    off = (off + 255) & ~(size_t)255;
    short* ab = (short*)(ws + off);               off += TB * 512 * 2;               // 128 MiB

    k_zero<<<1, 64, 0, stream>>>(counts);
    k_prep_weights<<<1024, 256, 0, stream>>>(W_ih, W_hh, b_ih, b_hh, Wb, bias);
    k_prep_wq<<<512, 256, 0, stream>>>(W_ih, W_hh, Wq);
    k_prep_ab<<<(int)(TB / 4), 256, 0, stream>>>(x, h0, done, (unsigned long long*)ab);
    k_kmap<<<T_DIM, 256, 0, stream>>>(done, kmap, counts);
    k_offs<<<1, 64, 0, stream>>>(counts, offs, cursor);
    k_scatter<<<(int)(TB / 256), 256, 0, stream>>>(kmap, offs, cursor, rowlist);

    // cooperative fused rounds (grid = 256 = 1 block/CU); fallback = 16 launches
    const short* ab_c = (const short*)ab;
    const short* Wb_s = (const short*)Wb;
    void* args[] = {(void*)&ab_c, (void*)&c0, (void*)&done, (void*)&Wb_s, (void*)&bias,
                    (void*)&counts, (void*)&offs, (void*)&rowlist,
                    (void*)&out, (void*)&c_buf, (void*)&ab};
    hipError_t ce = hipLaunchCooperativeKernel((void*)k_rounds_coop,
                                               dim3(256), dim3(512), args, 0, stream);
    if (ce != hipSuccess) {
        int est = 70000;
        for (int k = 0; k < CHAIN_K; ++k) {
            int rgs = (est + 31) / 32;
            if (rgs > 64) rgs = 64;
            if (rgs < 1) rgs = 1;
            k_round<<<4 * rgs, 512, 0, stream>>>(ab_c, c0, done, Wb_s, bias,
                                                 counts, offs, rowlist, out, c_buf, ab, k);
            est >>= 1;
        }
    }
    k_finish<<<64, 1024, 0, stream>>>(x, Wq, bias, counts, offs, rowlist, kmap, out, c_buf);
    k_final<<<B_DIM * H_DIM / 256, 256, 0, stream>>>(c_buf, out);
}

// Round 23
// 550.359 us; speedup vs baseline: 3.6369x; 3.6369x over previous
//
#include <hip/hip_runtime.h>
#include <math.h>

#define T_DIM 512
#define B_DIM 256
#define D_DIM 256
#define H_DIM 256
#define G_DIM 1024   // 4*H
#define K_DIM 512    // D + H
#define NROUNDS 40
#define CHAIN_K 16   // rounds 0..15 batched; steps >=16 via per-segment finisher

typedef __attribute__((ext_vector_type(8))) short short8;
typedef __attribute__((ext_vector_type(4))) float f32x4;

__device__ __forceinline__ unsigned int f2bf(float f) {
    unsigned int b = __float_as_uint(f);
    return (b + 0x7FFFu + ((b >> 16) & 1u)) >> 16;   // round-to-nearest-even bf16
}
__device__ __forceinline__ unsigned long long pack4(float4 v) {
    const unsigned int lo = (f2bf(v.y) << 16) | f2bf(v.x);
    const unsigned int hi = (f2bf(v.w) << 16) | f2bf(v.z);
    return ((unsigned long long)hi << 32) | lo;
}
__device__ __forceinline__ float sigm(float x) { return 1.0f / (1.0f + __expf(-x)); }
__device__ __forceinline__ float tanh_fast(float x) { return 2.0f / (1.0f + __expf(-2.0f * x)) - 1.0f; }

// async 16B/lane global->LDS (dest = wave-uniform base + lane*16; SOURCE is per-lane)
__device__ __forceinline__ void dma16(const void* g, void* l) {
    __builtin_amdgcn_global_load_lds(
        (const __attribute__((address_space(1))) void*)g,
        (__attribute__((address_space(3))) void*)l, 16, 0, 0);
}

// Prepack W into MFMA B-fragment order, bf16.
// short idx ((nt*16+ks)*64+l)*8+j  <->  g = nt*16+(l&15), k = ks*32+((l>>4)<<3)+j
__global__ __launch_bounds__(256) void k_prep_weights(
    const float* __restrict__ W_ih, const float* __restrict__ W_hh,
    const float* __restrict__ b_ih, const float* __restrict__ b_hh,
    unsigned int* __restrict__ Wb, float* __restrict__ bias)
{
    const int idx = blockIdx.x * 256 + threadIdx.x;   // 0 .. 262143
    const int jp = idx & 3, l = (idx >> 2) & 63, ks = (idx >> 8) & 15, nt = idx >> 12;
    const int g = nt * 16 + (l & 15);
    const int k0 = ks * 32 + ((l >> 4) << 3) + 2 * jp;
    const float w0 = (k0 < D_DIM) ? W_ih[g * D_DIM + k0] : W_hh[g * H_DIM + (k0 - D_DIM)];
    const float w1 = (k0 + 1 < D_DIM) ? W_ih[g * D_DIM + k0 + 1] : W_hh[g * H_DIM + (k0 + 1 - D_DIM)];
    Wb[idx] = (f2bf(w1) << 16) | f2bf(w0);
    if (idx < G_DIM) bias[idx] = b_ih[idx] + b_hh[idx];
}

// Prepack W k-major for the finisher GEMV.
__global__ __launch_bounds__(256) void k_prep_wq(
    const float* __restrict__ W_ih, const float* __restrict__ W_hh,
    unsigned long long* __restrict__ Wq)
{
    const int idx = blockIdx.x * 256 + threadIdx.x;   // 0..131071
    const int kq = idx >> 10, g = idx & (G_DIM - 1);
    float w[4];
    #pragma unroll
    for (int j = 0; j < 4; ++j) {
        const int k = kq * 4 + j;
        w[j] = (k < D_DIM) ? W_ih[g * D_DIM + k] : W_hh[g * H_DIM + (k - D_DIM)];
    }
    Wq[idx] = pack4((float4){w[0], w[1], w[2], w[3]});
}

// Fused ab prep: wave = one pos row. x-half bf16 (coalesced 1KB read -> 512B write)
// + h-half prefill for reset rows (done==1 -> 0) and t==0 rows (!done -> h0).
__global__ __launch_bounds__(256) void k_prep_ab(
    const float* __restrict__ x, const float* __restrict__ h0,
    const int* __restrict__ done, unsigned long long* __restrict__ ab_u64)
{
    const int pos = (blockIdx.x * 256 + threadIdx.x) >> 6;   // row = wave index
    const int l = threadIdx.x & 63;
    const float4 xv = *(const float4*)(x + (size_t)pos * D_DIM + l * 4);
    ab_u64[(size_t)pos * 128 + l] = pack4(xv);               // x-half slots [0,64)
    const int d = done[pos];
    if (d || pos < B_DIM) {
        unsigned long long hv = 0ull;
        if (!d) {   // t==0 row, carry h0
            const float4 h = *(const float4*)(h0 + (size_t)(pos & (B_DIM - 1)) * H_DIM + l * 4);
            hv = pack4(h);
        }
        ab_u64[(size_t)pos * 128 + 64 + l] = hv;             // h-half slots [64,128)
    }
}

// Parallel kmap + histogram (kmap = TRUE steps since reset; bins clamp).
__global__ __launch_bounds__(256) void k_kmap(
    const int* __restrict__ done, int* __restrict__ kmap, int* __restrict__ counts)
{
    __shared__ int lcnt[NROUNDS];
    const int tid = threadIdx.x;
    if (tid < NROUNDS) lcnt[tid] = 0;
    __syncthreads();
    const int t = blockIdx.x, b = tid;
    int kv = t;
    for (int tt = t; tt >= 0; --tt) {
        if (done[tt * B_DIM + b]) { kv = t - tt; break; }
    }
    kmap[t * B_DIM + b] = kv;
    const int bin = kv < NROUNDS ? kv : NROUNDS - 1;
    atomicAdd(&lcnt[bin], 1);
    __syncthreads();
    if (tid < NROUNDS && lcnt[tid] > 0) atomicAdd(&counts[tid], lcnt[tid]);
}

__global__ __launch_bounds__(64) void k_offs(
    const int* __restrict__ counts, int* __restrict__ offs, int* __restrict__ cursor)
{
    if (threadIdx.x == 0) {
        int s = 0;
        for (int i = 0; i < NROUNDS; ++i) { offs[i] = s; s += counts[i]; }
    }
    if (threadIdx.x < NROUNDS) cursor[threadIdx.x] = 0;
}

// Two-level scatter: LDS local ranks + one global atomicAdd per (block, bin).
__global__ __launch_bounds__(256) void k_scatter(
    const int* __restrict__ kmap, const int* __restrict__ offs,
    int* __restrict__ cursor, int* __restrict__ rowlist)
{
    __shared__ int lcnt[NROUNDS];
    __shared__ int gbase[NROUNDS];
    const int tid = threadIdx.x;
    if (tid < NROUNDS) lcnt[tid] = 0;
    __syncthreads();
    const int pos = blockIdx.x * 256 + tid;
    const int kv0 = kmap[pos];
    const int kv = kv0 < NROUNDS ? kv0 : NROUNDS - 1;
    const int lrank = atomicAdd(&lcnt[kv], 1);
    __syncthreads();
    if (tid < NROUNDS && lcnt[tid] > 0) gbase[tid] = atomicAdd(&cursor[tid], lcnt[tid]);
    __syncthreads();
    rowlist[offs[kv] + gbase[kv] + lrank] = pos;
}

// ================== champion round (measured 550.9us total) ==================
// 4 col-blocks (cb) of 256 gates (64 units). Block 512 thr (8 waves).
// Wave w: q=w&3, gth=w>>2; owns nt(uq) = (2*gth+uq)*16 + cb*4 + q (uq 0,1).
// XCD map (grid==256): the 4 cb blocks of one row-chain share an XCD L2.
// Hoisted loads: pos/c/done for tile N carried in regs from tile N-1's head.
__global__ __launch_bounds__(512, 1) void k_round(
    const short* __restrict__ ab, const float* __restrict__ c0,
    const int* __restrict__ done,
    const short* __restrict__ Wb, const float* __restrict__ bias,
    const int* __restrict__ counts, const int* __restrict__ offs,
    const int* __restrict__ rowlist,
    float* __restrict__ out, float* __restrict__ c_buf,
    short* __restrict__ ab_w, int kk)
{
    __shared__ short A_lds[2 * 32 * 512];        // 64 KiB (2 bufs x 32 rows x 1KB)
    __shared__ float scr[4 * 64 * 36];           // 36 KiB gate exchange
    const int nk = counts[kk];
    const int base = offs[kk];
    const int ntiles = (nk + 31) >> 5;

    int cb, rt, rstride;
    if (gridDim.x == 256) {                      // XCD-aware: same-rchain cbs share XCD
        const int xcd = blockIdx.x & 7, slot = blockIdx.x >> 3;
        cb = slot & 3;
        rt = xcd * 8 + (slot >> 2);
        rstride = 64;
    } else {
        cb = blockIdx.x & 3;
        rt = blockIdx.x >> 2;
        rstride = gridDim.x >> 2;
    }
    if (rt >= ntiles) return;                    // block-uniform exit

    const int tid = threadIdx.x;
    const int w = tid >> 6, l = tid & 63;
    const int lr = l >> 4, lc = l & 15;
    const int q = w & 3, gth = w >> 2;

    const int u_ep = cb * 64 + l;                // epilogue unit
    const float bI = bias[u_ep], bF = bias[256 + u_ep], bG = bias[512 + u_ep], bO = bias[768 + u_ep];

#define ISSUE_A(PP, bufv)                                                        \
    {                                                                            \
        _Pragma("unroll") for (int rr = 0; rr < 4; ++rr) {                       \
            const int r_ = w * 4 + rr;                                           \
            dma16(ab + (size_t)PP[rr] * 512 + ((l ^ (r_ & 15)) << 3),            \
                  &A_lds[(bufv) * 16384 + r_ * 512]);                            \
        }                                                                        \
    }
#define LOAD_NEXT(row0v, PP, CP, DN, DS)                                         \
    {                                                                            \
        _Pragma("unroll") for (int j_ = 0; j_ < 4; ++j_) {                       \
            const int gr_ = (row0v) + w * 4 + j_;                                \
            PP[j_] = rowlist[base + (gr_ < nk ? gr_ : nk - 1)];                  \
        }                                                                        \
        _Pragma("unroll") for (int j_ = 0; j_ < 4; ++j_) {                       \
            const int p_ = PP[j_];                                               \
            if (kk > 0) {                                                        \
                CP[j_] = c_buf[(size_t)(p_ - B_DIM) * H_DIM + u_ep];             \
                DN[j_] = 0;                                                      \
            } else {                                                             \
                DN[j_] = done[p_];                                               \
                CP[j_] = c0[(size_t)(p_ & (B_DIM - 1)) * H_DIM + u_ep];          \
            }                                                                    \
            const int sp_ = p_ + B_DIM;                                          \
            DS[j_] = (sp_ < T_DIM * B_DIM) ? done[sp_] : 1;                      \
        }                                                                        \
    }

    // ---- prologue: tile0 gather state + A-DMA + B-regs ----
    int posC[4], dnC[4], dsC[4]; float cpC[4];
    LOAD_NEXT(rt * 32, posC, cpC, dnC, dsC);
    ISSUE_A(posC, 0);
    short8 breg0[16], breg1[16];
    {
        const int nt0 = (2 * gth + 0) * 16 + cb * 4 + q;
        const int nt1 = (2 * gth + 1) * 16 + cb * 4 + q;
        #pragma unroll
        for (int ks = 0; ks < 16; ++ks) {
            breg0[ks] = *(const short8*)(Wb + (((size_t)nt0 * 16 + ks) * 64 + l) * 8);
            breg1[ks] = *(const short8*)(Wb + (((size_t)nt1 * 16 + ks) * 64 + l) * 8);
        }
        #pragma unroll
        for (int ks = 0; ks < 16; ++ks) {
            asm volatile("" : "+v"(breg0[ks]));
            asm volatile("" : "+v"(breg1[ks]));
        }
    }

    int buf = 0;
    for (; rt < ntiles; rt += rstride) {
        const int row0 = rt * 32;

        // head: A(cur)+carried loads landed; sync; issue next tile's gather+DMA
        asm volatile("s_waitcnt vmcnt(0) lgkmcnt(0)" ::: "memory");
        __builtin_amdgcn_sched_barrier(0);
        __builtin_amdgcn_s_barrier();
        __builtin_amdgcn_sched_barrier(0);
        const int rtn = rt + rstride;
        const bool more = (rtn < ntiles);
        int posN[4], dnN[4], dsN[4]; float cpN[4];
        if (more) {
            LOAD_NEXT(rtn * 32, posN, cpN, dnN, dsN);
            ISSUE_A(posN, buf ^ 1);
        }

        // compute: 32 a-reads x 2 MFMA each, B from resident regs
        f32x4 acc0[2], acc1[2];
        #pragma unroll
        for (int mb = 0; mb < 2; ++mb) { acc0[mb] = (f32x4){0,0,0,0}; acc1[mb] = (f32x4){0,0,0,0}; }
        #pragma unroll
        for (int ks = 0; ks < 16; ++ks) {
            #pragma unroll
            for (int mb = 0; mb < 2; ++mb) {
                const short8 a = *(const short8*)&A_lds[buf * 16384 + (mb * 16 + lc) * 512
                                                       + (((ks * 4 + lr) ^ lc) << 3)];
                acc0[mb] = __builtin_amdgcn_mfma_f32_16x16x32_bf16(a, breg0[ks], acc0[mb], 0, 0, 0);
                acc1[mb] = __builtin_amdgcn_mfma_f32_16x16x32_bf16(a, breg1[ks], acc1[mb], 0, 0, 0);
            }
        }

        // gate exchange: scr[gt][unit][row(+pad36)]
        #pragma unroll
        for (int mb = 0; mb < 2; ++mb) {
            *(f32x4*)&scr[(((2 * gth + 0) * 64 + q * 16 + lc) * 36) + mb * 16 + lr * 4] = acc0[mb];
            *(f32x4*)&scr[(((2 * gth + 1) * 64 + q * 16 + lc) * 36) + mb * 16 + lr * 4] = acc1[mb];
        }
        asm volatile("s_waitcnt lgkmcnt(0)" ::: "memory");
        __builtin_amdgcn_sched_barrier(0);
        __builtin_amdgcn_s_barrier();
        __builtin_amdgcn_sched_barrier(0);

        // epilogue: load-free (pos/c/done carried in regs)
        const f32x4 vi = *(const f32x4*)&scr[((0 * 64 + l) * 36) + w * 4];
        const f32x4 vf = *(const f32x4*)&scr[((1 * 64 + l) * 36) + w * 4];
        const f32x4 vg = *(const f32x4*)&scr[((2 * 64 + l) * 36) + w * 4];
        const f32x4 vo = *(const f32x4*)&scr[((3 * 64 + l) * 36) + w * 4];
        #pragma unroll
        for (int j = 0; j < 4; ++j) {
            const int gr = row0 + w * 4 + j;
            if (gr < nk) {
                const int pos = posC[j];
                const float cp = dnC[j] ? 0.0f : cpC[j];
                const float si = sigm(vi[j] + bI);
                const float sf = sigm(vf[j] + bF);
                const float tg = tanh_fast(vg[j] + bG);
                const float so = sigm(vo[j] + bO);
                const float cn = sf * cp + si * tg;
                const float hn = so * tanh_fast(cn);
                c_buf[(size_t)pos * H_DIM + u_ep] = cn;
                out[(size_t)pos * H_DIM + u_ep]  = hn;
                if (kk + 1 < CHAIN_K && !dsC[j]) {
                    ab_w[(size_t)(pos + B_DIM) * 512 + 256 + u_ep] = (short)f2bf(hn);
                }
            }
        }

        #pragma unroll
        for (int j = 0; j < 4; ++j) { posC[j] = posN[j]; cpC[j] = cpN[j]; dnC[j] = dnN[j]; dsC[j] = dsN[j]; }
        buf ^= 1;
    }
#undef ISSUE_A
#undef LOAD_NEXT
}

// Per-segment sequential finisher for steps >= CHAIN_K (independent chains).
__global__ __launch_bounds__(1024) void k_finish(
    const float* __restrict__ x, const unsigned long long* __restrict__ Wq,
    const float* __restrict__ bias,
    const int* __restrict__ counts, const int* __restrict__ offs,
    const int* __restrict__ rowlist, const int* __restrict__ kmap,
    float* __restrict__ out, float* __restrict__ c_buf)
{
    __shared__ float abuf[K_DIM];
    __shared__ float dots[G_DIM];
    const int g = threadIdx.x;
    const int nch = counts[CHAIN_K];

    for (int m = blockIdx.x; m < nch; m += gridDim.x) {
        const int pos0 = rowlist[offs[CHAIN_K] + m];
        float c_u = 0.0f;
        if (g < H_DIM) {
            abuf[H_DIM + g] = out[(size_t)(pos0 - B_DIM) * H_DIM + g];
            c_u = c_buf[(size_t)(pos0 - B_DIM) * H_DIM + g];
        }
        int pos = pos0, step = CHAIN_K;
        while (true) {
            if (g < H_DIM) abuf[g] = x[(size_t)pos * D_DIM + g];
            __syncthreads();
            float dot = bias[g];
            #pragma unroll 8
            for (int kq = 0; kq < K_DIM / 4; ++kq) {
                const unsigned long long wq = Wq[(size_t)kq * G_DIM + g];
                const float4 a = *(const float4*)&abuf[kq * 4];
                const unsigned int wlo = (unsigned int)wq;
                const unsigned int whi = (unsigned int)(wq >> 32);
                const float w0 = __uint_as_float(wlo << 16);
                const float w1 = __uint_as_float(wlo & 0xFFFF0000u);
                const float w2 = __uint_as_float(whi << 16);
                const float w3 = __uint_as_float(whi & 0xFFFF0000u);
                dot = fmaf(a.x, w0, dot);
                dot = fmaf(a.y, w1, dot);
                dot = fmaf(a.z, w2, dot);
                dot = fmaf(a.w, w3, dot);
            }
            dots[g] = dot;
            __syncthreads();
            if (g < H_DIM) {
                const float si = sigm(dots[g]);
                const float sf = sigm(dots[H_DIM + g]);
                const float tg = tanh_fast(dots[2 * H_DIM + g]);
                const float so = sigm(dots[3 * H_DIM + g]);
                c_u = sf * c_u + si * tg;
                const float hn = so * tanh_fast(c_u);
                out[(size_t)pos * H_DIM + g]   = hn;
                c_buf[(size_t)pos * H_DIM + g] = c_u;
                abuf[H_DIM + g] = hn;
            }
            pos += B_DIM;
            ++step;
            __syncthreads();
            if (pos >= T_DIM * B_DIM) break;
            if (kmap[pos] != step) break;
        }
        __syncthreads();
    }
}

// hT = out rows at t=511 ; cT = c_buf at t=511
__global__ __launch_bounds__(256) void k_final(const float* __restrict__ c_buf, float* __restrict__ out)
{
    const size_t i = (size_t)blockIdx.x * 256 + threadIdx.x;
    const size_t featN = (size_t)T_DIM * B_DIM * H_DIM;
    const size_t last  = (size_t)(T_DIM - 1) * B_DIM * H_DIM;
    out[featN + i] = out[last + i];
    out[featN + (size_t)B_DIM * H_DIM + i] = c_buf[last + i];
}

__global__ __launch_bounds__(64) void k_zero(int* __restrict__ counts)
{
    if (threadIdx.x < NROUNDS) counts[threadIdx.x] = 0;
}

extern "C" void kernel_launch(void* const* d_in, const int* in_sizes, int n_in,
                              void* d_out, int out_size, void* d_ws, size_t ws_size,
                              hipStream_t stream)
{
    const float* x    = (const float*)d_in[0];
    const float* h0   = (const float*)d_in[1];
    const float* c0   = (const float*)d_in[2];
    const float* W_ih = (const float*)d_in[3];
    const float* W_hh = (const float*)d_in[4];
    const float* b_ih = (const float*)d_in[5];
    const float* b_hh = (const float*)d_in[6];
    const int*   done = (const int*)d_in[7];
    float* out = (float*)d_out;

    const size_t TB = (size_t)T_DIM * B_DIM;
    char* ws = (char*)d_ws;
    size_t off = 0;
    float* c_buf = (float*)(ws + off);            off += TB * H_DIM * 4;            // 128 MiB
    unsigned int* Wb = (unsigned int*)(ws + off); off += (size_t)(K_DIM / 2) * G_DIM * 4;
    unsigned long long* Wq = (unsigned long long*)(ws + off); off += (size_t)(K_DIM / 4) * G_DIM * 8;
    float* bias = (float*)(ws + off);             off += (size_t)G_DIM * 4;
    int* kmap    = (int*)(ws + off);              off += TB * 4;
    int* rowlist = (int*)(ws + off);              off += TB * 4;
    int* counts  = (int*)(ws + off);              off += 256;
    int* offs    = (int*)(ws + off);              off += 256;
    int* cursor  = (int*)(ws + off);              off += 256;
    off = (off + 255) & ~(size_t)255;
    short* ab = (short*)(ws + off);               off += TB * 512 * 2;               // 128 MiB

    k_zero<<<1, 64, 0, stream>>>(counts);
    k_prep_weights<<<1024, 256, 0, stream>>>(W_ih, W_hh, b_ih, b_hh, Wb, bias);
    k_prep_wq<<<512, 256, 0, stream>>>(W_ih, W_hh, Wq);
    k_prep_ab<<<(int)(TB / 4), 256, 0, stream>>>(x, h0, done, (unsigned long long*)ab);
    k_kmap<<<T_DIM, 256, 0, stream>>>(done, kmap, counts);
    k_offs<<<1, 64, 0, stream>>>(counts, offs, cursor);
    k_scatter<<<(int)(TB / 256), 256, 0, stream>>>(kmap, offs, cursor, rowlist);

    int est = 70000;   // statistical upper bound on round-0 rows; ~halves each round
    for (int k = 0; k < CHAIN_K; ++k) {
        int rgs = (est + 31) / 32;
        if (rgs > 64) rgs = 64;
        if (rgs < 1) rgs = 1;
        k_round<<<4 * rgs, 512, 0, stream>>>((const short*)ab, c0, done, (const short*)Wb,
                                             bias, counts, offs, rowlist, out, c_buf, ab, k);
        est >>= 1;
    }
    k_finish<<<64, 1024, 0, stream>>>(x, Wq, bias, counts, offs, rowlist, kmap, out, c_buf);
    k_final<<<B_DIM * H_DIM / 256, 256, 0, stream>>>(c_buf, out);
}